// Round 2
// baseline (1022.637 us; speedup 1.0000x reference)
//
#include <hip/hip_runtime.h>
#include <cstdint>
#include <cstring>

// VQR circuit simulator: 16 qubits, B=512, 4 layers.
// CNOTs are GF(2) index-relabeling bookkeeping (host-side, structural,
// deterministic). Only fused 1q gates touch data, applied as XOR-mask pair
// rotations on 8192-amp LDS-resident chunks. Passes are in-place over the
// state in d_ws; batch is chunked into groups sized to fit ws_size.

struct PassMeta {
    int      ngates;
    uint16_t gmask[24];      // pair-partner XOR mask (packed 13-bit LDS index space)
    uint16_t grow[24];       // branch parity mask over local packed bits
    uint8_t  gnl[24];        // branch parity mask over the 3 chunk bits (c)
    uint8_t  ggidx[24];      // gate matrix index l*16+w
    uint8_t  gap[3];         // non-local bit positions, ASCENDING
    uint8_t  wire_of_bit[13];// packed LDS bit -> wire (for product-state init)
    uint8_t  nlw[3];         // chunk bit k -> wire (aligned with gap[k])
    uint16_t meas_row_local; // measurement parity mask (local bits)
    uint8_t  meas_nl;        // measurement parity mask (chunk bits)
};

__device__ __forceinline__ float2 cmul(float2 a, float2 b) {
    return make_float2(a.x * b.x - a.y * b.y, a.x * b.y + a.y * b.x);
}

// Fused 2x2 unitary U = Rz(t2)Ry(t1)Rz(t0)Rx(enc), enc = 2*atan(x).
__global__ __launch_bounds__(512)
void precompute_kernel(const float* __restrict__ X, const float* __restrict__ Wt,
                       const float* __restrict__ Bs, float2* __restrict__ Ug,
                       float* __restrict__ out)
{
    int id = blockIdx.x * 512 + threadIdx.x;
    if (id >= 512 * 64) return;
    int b = id >> 6, lw = id & 63, l = lw >> 4, w = lw & 15;
    float x  = X[b * 16 + w];
    float ce = 1.0f / sqrtf(1.0f + x * x);
    float se = x * ce;
    float t0 = 0.5f * Wt[(l * 16 + w) * 3 + 0];
    float t1 = 0.5f * Wt[(l * 16 + w) * 3 + 1];
    float t2 = 0.5f * Wt[(l * 16 + w) * 3 + 2];
    float c1 = cosf(t1), s1 = sinf(t1);
    float ca = cosf(t0 + t2), sa = sinf(t0 + t2);
    float cb = cosf(t2 - t0), sb = sinf(t2 - t0);
    float2 W00 = make_float2( c1 * ca, -c1 * sa);
    float2 W01 = make_float2(-s1 * cb,  s1 * sb);
    float2 W10 = make_float2( s1 * cb,  s1 * sb);
    float2 W11 = make_float2( c1 * ca,  c1 * sa);
    float2 U00 = make_float2(W00.x * ce + W01.y * se, W00.y * ce - W01.x * se);
    float2 U01 = make_float2(W00.y * se + W01.x * ce, -W00.x * se + W01.y * ce);
    float2 U10 = make_float2(W10.x * ce + W11.y * se, W10.y * ce - W11.x * se);
    float2 U11 = make_float2(W10.y * se + W11.x * ce, -W10.x * se + W11.y * ce);
    float2* dst = Ug + (size_t)id * 4;
    dst[0] = U00; dst[1] = U01; dst[2] = U10; dst[3] = U11;
    if (lw == 0) out[b] = Bs[0];   // init output with bias before final-pass atomics
}

// MODE 0: generate product state + gates + store
// MODE 1: load + gates + store (in-place)
// MODE 2: load + gates + measurement reduce (no store)
template <int MODE>
__global__ __launch_bounds__(512)
void pass_kernel(const float2* __restrict__ Ug, float2* __restrict__ state,
                 float* __restrict__ out, PassMeta meta)
{
    __shared__ float2 amp[8192];   // 64 KiB
    const int tid = threadIdx.x;
    const int bb  = blockIdx.x >> 3;
    const unsigned c = blockIdx.x & 7;
    const size_t base = ((size_t)bb) << 16;
    const float2* Ub = Ug + (size_t)bb * 256;
    const unsigned g0 = meta.gap[0], g1 = meta.gap[1], g2 = meta.gap[2];
    const unsigned cb0 = c & 1u, cb1 = (c >> 1) & 1u, cb2 = (c >> 2) & 1u;

    auto expand = [&](unsigned x) -> unsigned {   // gaps ascending (host-sorted)
        x = ((x >> g0) << (g0 + 1)) | (x & ((1u << g0) - 1u)) | (cb0 << g0);
        x = ((x >> g1) << (g1 + 1)) | (x & ((1u << g1) - 1u)) | (cb1 << g1);
        x = ((x >> g2) << (g2 + 1)) | (x & ((1u << g2) - 1u)) | (cb2 << g2);
        return x;
    };

    if constexpr (MODE == 0) {
        if (tid == 0) {
            float2 k = make_float2(1.f, 0.f);
            const unsigned cbs[3] = {cb0, cb1, cb2};
            for (int t = 0; t < 3; ++t) {
                float2 v = Ub[(int)meta.nlw[t] * 4 + (cbs[t] ? 2 : 0)];
                k = cmul(k, v);
            }
            amp[0] = k;
        }
        __syncthreads();
        for (int s = 0; s < 13; ++s) {
            const int n = 1 << s;
            const float2 v0 = Ub[(int)meta.wire_of_bit[s] * 4 + 0];
            const float2 v1 = Ub[(int)meta.wire_of_bit[s] * 4 + 2];
            for (int u = tid; u < n; u += 512) {
                float2 a = amp[u];
                amp[u + n] = cmul(a, v1);
                amp[u]     = cmul(a, v0);
            }
            __syncthreads();
        }
    } else {
        for (int it = 0; it < 8; ++it) {
            unsigned u = (unsigned)(tid + it * 512) * 2u;
            unsigned a = expand(u);
            float4 v = *reinterpret_cast<const float4*>(state + base + a);
            amp[u]     = make_float2(v.x, v.y);
            amp[u + 1] = make_float2(v.z, v.w);
        }
        __syncthreads();
    }

    for (int gi = 0; gi < meta.ngates; ++gi) {
        const unsigned m   = meta.gmask[gi];
        const unsigned row = meta.grow[gi];
        const unsigned bp  = (unsigned)(__popc((unsigned)meta.gnl[gi] & c) & 1);
        const float2* Um = Ub + (int)meta.ggidx[gi] * 4;
        const float2 u00 = Um[0], u01 = Um[1], u10 = Um[2], u11 = Um[3];
        const unsigned b0  = (unsigned)__ffs((int)m) - 1u;
        const unsigned lom = (1u << b0) - 1u;
        #pragma unroll
        for (int k = 0; k < 8; ++k) {
            const unsigned pid = (unsigned)(tid + k * 512);
            const unsigned i  = ((pid & ~lom) << 1) | (pid & lom);
            const unsigned j  = i ^ m;
            const unsigned p  = (unsigned)((__popc(i & row) + bp) & 1);
            const unsigned i0 = p ? j : i;
            const unsigned i1 = p ? i : j;
            const float2 a0 = amp[i0];
            const float2 a1 = amp[i1];
            float2 n0, n1;
            n0.x = a0.x * u00.x - a0.y * u00.y + a1.x * u01.x - a1.y * u01.y;
            n0.y = a0.x * u00.y + a0.y * u00.x + a1.x * u01.y + a1.y * u01.x;
            n1.x = a0.x * u10.x - a0.y * u10.y + a1.x * u11.x - a1.y * u11.y;
            n1.y = a0.x * u10.y + a0.y * u10.x + a1.x * u11.y + a1.y * u11.x;
            amp[i0] = n0;
            amp[i1] = n1;
        }
        __syncthreads();
    }

    if constexpr (MODE == 2) {
        float acc = 0.f;
        const unsigned mrow = meta.meas_row_local;
        const unsigned mbp  = (unsigned)(__popc((unsigned)meta.meas_nl & c) & 1);
        for (int k = 0; k < 16; ++k) {
            const unsigned u = (unsigned)(tid + k * 512);
            const float2 a = amp[u];
            const float t = a.x * a.x + a.y * a.y;
            acc += ((__popc(u & mrow) + mbp) & 1) ? -t : t;
        }
        for (int off = 32; off > 0; off >>= 1) acc += __shfl_down(acc, off, 64);
        if ((tid & 63) == 0) atomicAdd(&out[bb], acc);
    } else {
        for (int it = 0; it < 8; ++it) {
            unsigned u = (unsigned)(tid + it * 512) * 2u;
            unsigned a = expand(u);
            float4 v = make_float4(amp[u].x, amp[u].y, amp[u + 1].x, amp[u + 1].y);
            *reinterpret_cast<float4*>(state + base + a) = v;
        }
    }
}

extern "C" void kernel_launch(void* const* d_in, const int* in_sizes, int n_in,
                              void* d_out, int out_size, void* d_ws, size_t ws_size,
                              hipStream_t stream)
{
    const float* X  = (const float*)d_in[0];
    const float* Wt = (const float*)d_in[1];
    const float* Bs = (const float*)d_in[2];
    float* out = (float*)d_out;

    // ws layout: Ug (1 MiB) first, then state for one batch-group.
    const size_t UG_BYTES = (size_t)512 * 64 * 4 * sizeof(float2);  // 1 MiB
    float2* Ug    = (float2*)d_ws;
    float2* state = (float2*)((char*)d_ws + UG_BYTES);
    size_t avail = ws_size > UG_BYTES ? ws_size - UG_BYTES : 0;
    int group = 1;
    while (group < 512 && (size_t)(group * 2) * (65536ull * sizeof(float2)) <= avail)
        group <<= 1;
    const int ngroups = 512 / group;

    // ---- host-side GF(2) bookkeeping (structural, identical every call) ----
    uint16_t D[16], R[16];
    for (int w = 0; w < 16; ++w) { D[w] = R[w] = (uint16_t)(1u << w); }
    struct G { uint16_t D, R; int gidx; int layer; bool pruned; bool sched; };
    G gl[48]; int ng = 0;
    for (int l = 1; l <= 3; ++l) {
        for (int w = 0; w < 16; ++w) { int t = (w + 1) & 15; D[w] ^= D[t]; R[t] ^= R[w]; }
        for (int w = 0; w < 16; ++w) gl[ng++] = G{D[w], R[w], l * 16 + w, l, false, false};
    }
    for (int w = 0; w < 16; ++w) { int t = (w + 1) & 15; D[w] ^= D[t]; R[t] ^= R[w]; }
    const uint16_t Rmeas = R[0];   // Z on logical wire 0 pulled back to final frame

    // Backward prune: drop gates commuting with every later kept op + measurement.
    uint16_t keptD[49], keptR[49]; int nk = 0;
    keptD[nk] = 0; keptR[nk] = Rmeas; ++nk;
    for (int i = ng - 1; i >= 0; --i) {
        bool comm = true;
        for (int k = 0; k < nk; ++k) {
            if (__builtin_parity((unsigned)(gl[i].D & keptR[k])) ||
                __builtin_parity((unsigned)(keptD[k] & gl[i].R))) { comm = false; break; }
        }
        if (comm) gl[i].pruned = true;
        else { keptD[nk] = gl[i].D; keptR[nk] = gl[i].R; ++nk; }
    }

    // Wire -> state-array bit position (fixed permutation; non-local wires high).
    static const int wireToPos[16] = {4,3,2,9,8,7,1,0,12,11,10,6,5,15,14,13};
    int posToWire[16];
    for (int w = 0; w < 16; ++w) posToWire[wireToPos[w]] = w;
    // Excluded (chunk) wire triples per pass window; cycled until all scheduled.
    static const int WIN[4][3] = {{13,14,15},{8,9,10},{3,4,5},{11,12,13}};

    // Schedule: only same-layer reordering (same-layer gates always commute:
    // parity(R_j & D_i) = (A^l A^-l)_{ji} = delta_ji). Cross-layer order kept.
    int pendLayer[4] = {0, 0, 0, 0};
    int totalPend = 0;
    for (int i = 0; i < ng; ++i)
        if (!gl[i].pruned) { pendLayer[gl[i].layer]++; totalPend++; }

    PassMeta pms[12];
    int np = 0;
    while ((totalPend > 0 || np < 2) && np < 12) {
        PassMeta& M = pms[np];
        memset(&M, 0, sizeof(M));
        const int* W = WIN[np % 4];
        // (pos, wire) pairs sorted ascending by pos — expand() requires it.
        int gp[3], gw[3];
        for (int k = 0; k < 3; ++k) { gp[k] = wireToPos[W[k]]; gw[k] = W[k]; }
        for (int a = 0; a < 3; ++a)
            for (int b = a + 1; b < 3; ++b)
                if (gp[b] < gp[a]) {
                    int t = gp[a]; gp[a] = gp[b]; gp[b] = t;
                    t = gw[a]; gw[a] = gw[b]; gw[b] = t;
                }
        uint16_t Smask = 0xFFFF;
        for (int k = 0; k < 3; ++k) {
            Smask &= (uint16_t)~(1u << gw[k]);
            M.gap[k] = (uint8_t)gp[k];
            M.nlw[k] = (uint8_t)gw[k];
        }
        int packedOfWire[16];
        for (int w = 0; w < 16; ++w) packedOfWire[w] = -1;
        int t = 0;
        for (int pos = 0; pos < 16; ++pos) {
            if (pos == gp[0] || pos == gp[1] || pos == gp[2]) continue;
            int w = posToWire[pos];
            M.wire_of_bit[t] = (uint8_t)w;
            packedOfWire[w] = t;
            ++t;
        }
        for (int i = 0; i < ng; ++i) {
            if (gl[i].pruned || gl[i].sched) continue;
            bool lowerDone = true;
            for (int m2 = 1; m2 < gl[i].layer; ++m2)
                if (pendLayer[m2] > 0) { lowerDone = false; break; }
            if (!lowerDone) continue;
            if (gl[i].D & ~Smask) continue;           // must fit local window
            gl[i].sched = true;
            pendLayer[gl[i].layer]--; totalPend--;
            int gi = M.ngates++;
            uint16_t m = 0, r = 0; uint8_t nl = 0;
            for (int w = 0; w < 16; ++w) {
                if ((gl[i].D >> w) & 1) m |= (uint16_t)(1u << packedOfWire[w]);
                if (((gl[i].R >> w) & 1) && packedOfWire[w] >= 0)
                    r |= (uint16_t)(1u << packedOfWire[w]);
            }
            for (int k = 0; k < 3; ++k)
                if ((gl[i].R >> gw[k]) & 1) nl |= (uint8_t)(1u << k);
            M.gmask[gi] = m; M.grow[gi] = r; M.gnl[gi] = nl;
            M.ggidx[gi] = (uint8_t)gl[i].gidx;
        }
        {   // measurement masks (used only if this pass ends up last)
            uint16_t r = 0; uint8_t nl = 0;
            for (int w = 0; w < 16; ++w)
                if (((Rmeas >> w) & 1) && packedOfWire[w] >= 0)
                    r |= (uint16_t)(1u << packedOfWire[w]);
            for (int k = 0; k < 3; ++k)
                if ((Rmeas >> gw[k]) & 1) nl |= (uint8_t)(1u << k);
            M.meas_row_local = r; M.meas_nl = nl;
        }
        ++np;
    }

    precompute_kernel<<<dim3(64), dim3(512), 0, stream>>>(X, Wt, Bs, Ug, out);
    for (int g = 0; g < ngroups; ++g) {
        const float2* ug = Ug + (size_t)g * group * 256;
        float* og = out + (size_t)g * group;
        dim3 grid(group * 8);
        for (int p = 0; p < np; ++p) {
            if (p == 0)
                pass_kernel<0><<<grid, dim3(512), 0, stream>>>(ug, state, og, pms[p]);
            else if (p == np - 1)
                pass_kernel<2><<<grid, dim3(512), 0, stream>>>(ug, state, og, pms[p]);
            else
                pass_kernel<1><<<grid, dim3(512), 0, stream>>>(ug, state, og, pms[p]);
        }
    }

    (void)in_sizes; (void)n_in; (void)out_size; (void)ws_size;
}

// Round 3
// 900.510 us; speedup vs baseline: 1.1356x; 1.1356x over previous
//
#include <hip/hip_runtime.h>
#include <cstdint>
#include <cstring>

// VQR circuit simulator: 16 qubits, B=512, 4 layers.
// CNOTs are GF(2) index-relabeling bookkeeping (host-side, structural,
// deterministic). Fused 1q gates are XOR-mask pair rotations applied on
// 8192-amp LDS-resident chunks. Gates are clustered in pairs: each thread
// loads a dim-2 coset {r, r^x, r^y, r^x^y} (4 amps) into registers, applies
// both gates in-register (branch-free cndmask value swap + packed-fp32
// complex MACs), writes back. Halves LDS traffic + barriers per gate.

typedef float v2f __attribute__((ext_vector_type(2)));

struct PassMeta {
    int      nclusters;
    uint16_t cx[12], cy[12];     // reduced coset basis (13-bit local masks)
    uint16_t rowA[12], rowB[12]; // branch parity masks (local bits)
    uint8_t  cq0[12], cq1[12];   // pivot bit positions, ascending
    uint8_t  gA[12], gB[12];     // gate matrix index l*16+w; gB=0xFF -> identity
    uint8_t  nlA[12], nlB[12];   // branch parity masks over the 3 chunk bits
    uint8_t  pyA[12];            // parity(y & rowA): beta offset of A's 2nd pair
    uint8_t  patB[12];           // B pairing pattern: 0:(01)(23) 1:(02)(13) 2:(03)(12)
    uint8_t  poffB[12];          // beta offset for B's 2nd pair
    uint8_t  gap[3];             // non-local bit positions, ASCENDING (all >=1)
    uint8_t  wire_of_bit[13];    // packed LDS bit -> wire (product-state init)
    uint8_t  nlw[3];             // chunk bit k -> wire (aligned with gap[k])
    uint16_t meas_row_local;     // measurement parity mask (local bits)
    uint8_t  meas_nl;            // measurement parity mask (chunk bits)
};

struct C4 { v2f u00, u00r, u01, u01r, u10, u10r, u11, u11r; };

__device__ __forceinline__ v2f cmulv(v2f a, v2f b) {
    return v2f{a.x * b.x - a.y * b.y, a.x * b.y + a.y * b.x};
}

__device__ __forceinline__ void load_c4(C4& g, const float2* U) {
    float2 a = U[0], b = U[1], c = U[2], d = U[3];
    g.u00 = v2f{a.x, a.y}; g.u00r = v2f{-a.y, a.x};
    g.u01 = v2f{b.x, b.y}; g.u01r = v2f{-b.y, b.x};
    g.u10 = v2f{c.x, c.y}; g.u10r = v2f{-c.y, c.x};
    g.u11 = v2f{d.x, d.y}; g.u11r = v2f{-d.y, d.x};
}

// One 2x2 gate on pair (p,q); beta = logical-bit value of p's basis state.
// 8 cndmask + 8 packed-FMA, branch-free.
__device__ __forceinline__ void apply_pair(v2f& p, v2f& q, unsigned beta, const C4& u) {
    v2f lo = beta ? q : p;            // 0-branch amplitude
    v2f hi = beta ? p : q;            // 1-branch amplitude
    v2f n0 = u.u00 * lo.x + u.u00r * lo.y + u.u01 * hi.x + u.u01r * hi.y;
    v2f n1 = u.u10 * lo.x + u.u10r * lo.y + u.u11 * hi.x + u.u11r * hi.y;
    p = beta ? n1 : n0;
    q = beta ? n0 : n1;
}

// Fused 2x2 unitary U = Rz(t2)Ry(t1)Rz(t0)Rx(enc), enc = 2*atan(x).
__global__ __launch_bounds__(512)
void precompute_kernel(const float* __restrict__ X, const float* __restrict__ Wt,
                       const float* __restrict__ Bs, float2* __restrict__ Ug,
                       float* __restrict__ out)
{
    int id = blockIdx.x * 512 + threadIdx.x;
    if (id >= 512 * 64) return;
    int b = id >> 6, lw = id & 63, l = lw >> 4, w = lw & 15;
    float x  = X[b * 16 + w];
    float ce = 1.0f / sqrtf(1.0f + x * x);
    float se = x * ce;
    float t0 = 0.5f * Wt[(l * 16 + w) * 3 + 0];
    float t1 = 0.5f * Wt[(l * 16 + w) * 3 + 1];
    float t2 = 0.5f * Wt[(l * 16 + w) * 3 + 2];
    float c1 = cosf(t1), s1 = sinf(t1);
    float ca = cosf(t0 + t2), sa = sinf(t0 + t2);
    float cb = cosf(t2 - t0), sb = sinf(t2 - t0);
    float2 W00 = make_float2( c1 * ca, -c1 * sa);
    float2 W01 = make_float2(-s1 * cb,  s1 * sb);
    float2 W10 = make_float2( s1 * cb,  s1 * sb);
    float2 W11 = make_float2( c1 * ca,  c1 * sa);
    float2 U00 = make_float2(W00.x * ce + W01.y * se, W00.y * ce - W01.x * se);
    float2 U01 = make_float2(W00.y * se + W01.x * ce, -W00.x * se + W01.y * ce);
    float2 U10 = make_float2(W10.x * ce + W11.y * se, W10.y * ce - W11.x * se);
    float2 U11 = make_float2(W10.y * se + W11.x * ce, -W10.x * se + W11.y * ce);
    float2* dst = Ug + (size_t)id * 4;
    dst[0] = U00; dst[1] = U01; dst[2] = U10; dst[3] = U11;
    if (lw == 0) out[b] = Bs[0];   // init output with bias before final-pass atomics
}

// MODE 0: generate product state + gates + store
// MODE 1: load + gates + store (in-place)
// MODE 2: load + gates + measurement reduce (no store)
template <int MODE>
__global__ __launch_bounds__(512)
void pass_kernel(const float2* __restrict__ Ug, float2* __restrict__ state,
                 float* __restrict__ out, PassMeta meta)
{
    __shared__ v2f amp[8192];   // 64 KiB
    const int tid = threadIdx.x;
    const int bb  = blockIdx.x >> 3;
    const unsigned c = blockIdx.x & 7;
    const size_t base = ((size_t)bb) << 16;
    const float2* Ub = Ug + (size_t)bb * 256;
    const unsigned g0 = meta.gap[0], g1 = meta.gap[1], g2 = meta.gap[2];
    const unsigned cb0 = c & 1u, cb1 = (c >> 1) & 1u, cb2 = (c >> 2) & 1u;

    auto expand = [&](unsigned x) -> unsigned {   // gaps ascending; all gaps >= 1
        x = ((x >> g0) << (g0 + 1)) | (x & ((1u << g0) - 1u)) | (cb0 << g0);
        x = ((x >> g1) << (g1 + 1)) | (x & ((1u << g1) - 1u)) | (cb1 << g1);
        x = ((x >> g2) << (g2 + 1)) | (x & ((1u << g2) - 1u)) | (cb2 << g2);
        return x;
    };

    if constexpr (MODE == 0) {
        if (tid == 0) {
            v2f k = v2f{1.f, 0.f};
            const unsigned cbs[3] = {cb0, cb1, cb2};
            for (int t = 0; t < 3; ++t) {
                float2 v = Ub[(int)meta.nlw[t] * 4 + (cbs[t] ? 2 : 0)];
                k = cmulv(k, v2f{v.x, v.y});
            }
            amp[0] = k;
        }
        __syncthreads();
        for (int s = 0; s < 13; ++s) {
            const int n = 1 << s;
            float2 w0 = Ub[(int)meta.wire_of_bit[s] * 4 + 0];
            float2 w1 = Ub[(int)meta.wire_of_bit[s] * 4 + 2];
            const v2f v0 = v2f{w0.x, w0.y}, v1 = v2f{w1.x, w1.y};
            for (int u = tid; u < n; u += 512) {
                v2f a = amp[u];
                amp[u + n] = cmulv(a, v1);
                amp[u]     = cmulv(a, v0);
            }
            __syncthreads();
        }
    } else {
        for (int it = 0; it < 8; ++it) {
            unsigned u = (unsigned)(tid + it * 512) * 2u;
            unsigned a = expand(u);   // gaps >= 1 so a, a+1 are contiguous
            float4 v = *reinterpret_cast<const float4*>(state + base + a);
            amp[u]     = v2f{v.x, v.y};
            amp[u + 1] = v2f{v.z, v.w};
        }
        __syncthreads();
    }

    for (int ci = 0; ci < meta.nclusters; ++ci) {
        const unsigned x = meta.cx[ci], y = meta.cy[ci];
        const unsigned q0 = meta.cq0[ci], q1 = meta.cq1[ci];
        C4 A, B;
        load_c4(A, Ub + (int)meta.gA[ci] * 4);
        if (meta.gB[ci] != 0xFF) {
            load_c4(B, Ub + (int)meta.gB[ci] * 4);
        } else {
            B.u00 = v2f{1.f, 0.f}; B.u00r = v2f{0.f, 1.f};
            B.u01 = v2f{0.f, 0.f}; B.u01r = v2f{0.f, 0.f};
            B.u10 = v2f{0.f, 0.f}; B.u10r = v2f{0.f, 0.f};
            B.u11 = v2f{1.f, 0.f}; B.u11r = v2f{0.f, 1.f};
        }
        const unsigned rowA = meta.rowA[ci], rowB = meta.rowB[ci];
        const unsigned bpA = (unsigned)(__popc((unsigned)meta.nlA[ci] & c) & 1);
        const unsigned bpB = (unsigned)(__popc((unsigned)meta.nlB[ci] & c) & 1);
        const unsigned pyA = meta.pyA[ci], poB = meta.poffB[ci];
        const unsigned pat = meta.patB[ci];
        #pragma unroll
        for (int k = 0; k < 4; ++k) {
            unsigned pid = (unsigned)tid + (unsigned)k * 512u;
            unsigned r = ((pid >> q0) << (q0 + 1)) | (pid & ((1u << q0) - 1u));
            r = ((r >> q1) << (q1 + 1)) | (r & ((1u << q1) - 1u));
            v2f a0 = amp[r];
            v2f a1 = amp[r ^ x];
            v2f a2 = amp[r ^ y];
            v2f a3 = amp[r ^ x ^ y];
            const unsigned bA = (unsigned)((__popc(r & rowA) + bpA) & 1);
            apply_pair(a0, a1, bA, A);
            apply_pair(a2, a3, bA ^ pyA, A);
            const unsigned bB = (unsigned)((__popc(r & rowB) + bpB) & 1);
            if (pat == 0)      { apply_pair(a0, a1, bB, B); apply_pair(a2, a3, bB ^ poB, B); }
            else if (pat == 1) { apply_pair(a0, a2, bB, B); apply_pair(a1, a3, bB ^ poB, B); }
            else               { apply_pair(a0, a3, bB, B); apply_pair(a1, a2, bB ^ poB, B); }
            amp[r]         = a0;
            amp[r ^ x]     = a1;
            amp[r ^ y]     = a2;
            amp[r ^ x ^ y] = a3;
        }
        __syncthreads();
    }

    if constexpr (MODE == 2) {
        float acc = 0.f;
        const unsigned mrow = meta.meas_row_local;
        const unsigned mbp  = (unsigned)(__popc((unsigned)meta.meas_nl & c) & 1);
        for (int k = 0; k < 16; ++k) {
            const unsigned u = (unsigned)(tid + k * 512);
            const v2f a = amp[u];
            const float t = a.x * a.x + a.y * a.y;
            acc += ((__popc(u & mrow) + mbp) & 1) ? -t : t;
        }
        for (int off = 32; off > 0; off >>= 1) acc += __shfl_down(acc, off, 64);
        if ((tid & 63) == 0) atomicAdd(&out[bb], acc);
    } else {
        for (int it = 0; it < 8; ++it) {
            unsigned u = (unsigned)(tid + it * 512) * 2u;
            unsigned a = expand(u);
            v2f lo = amp[u], hi = amp[u + 1];
            float4 v = make_float4(lo.x, lo.y, hi.x, hi.y);
            *reinterpret_cast<float4*>(state + base + a) = v;
        }
    }
}

extern "C" void kernel_launch(void* const* d_in, const int* in_sizes, int n_in,
                              void* d_out, int out_size, void* d_ws, size_t ws_size,
                              hipStream_t stream)
{
    const float* X  = (const float*)d_in[0];
    const float* Wt = (const float*)d_in[1];
    const float* Bs = (const float*)d_in[2];
    float* out = (float*)d_out;

    // ws layout: Ug (1 MiB) first, then state for one batch-group.
    const size_t UG_BYTES = (size_t)512 * 64 * 4 * sizeof(float2);  // 1 MiB
    float2* Ug    = (float2*)d_ws;
    float2* state = (float2*)((char*)d_ws + UG_BYTES);
    size_t avail = ws_size > UG_BYTES ? ws_size - UG_BYTES : 0;
    int group = 1;
    while (group < 512 && (size_t)(group * 2) * (65536ull * sizeof(float2)) <= avail)
        group <<= 1;
    const int ngroups = 512 / group;

    // ---- host-side GF(2) bookkeeping (structural, identical every call) ----
    uint16_t D[16], R[16];
    for (int w = 0; w < 16; ++w) { D[w] = R[w] = (uint16_t)(1u << w); }
    struct G { uint16_t D, R; int gidx; int layer; bool pruned; bool sched; };
    G gl[48]; int ng = 0;
    for (int l = 1; l <= 3; ++l) {
        for (int w = 0; w < 16; ++w) { int t = (w + 1) & 15; D[w] ^= D[t]; R[t] ^= R[w]; }
        for (int w = 0; w < 16; ++w) gl[ng++] = G{D[w], R[w], l * 16 + w, l, false, false};
    }
    for (int w = 0; w < 16; ++w) { int t = (w + 1) & 15; D[w] ^= D[t]; R[t] ^= R[w]; }
    const uint16_t Rmeas = R[0];   // Z on logical wire 0 pulled back to final frame

    // Backward prune: drop gates commuting with every later kept op + measurement.
    uint16_t keptD[49], keptR[49]; int nk = 0;
    keptD[nk] = 0; keptR[nk] = Rmeas; ++nk;
    for (int i = ng - 1; i >= 0; --i) {
        bool comm = true;
        for (int k = 0; k < nk; ++k) {
            if (__builtin_parity((unsigned)(gl[i].D & keptR[k])) ||
                __builtin_parity((unsigned)(keptD[k] & gl[i].R))) { comm = false; break; }
        }
        if (comm) gl[i].pruned = true;
        else { keptD[nk] = gl[i].D; keptR[nk] = gl[i].R; ++nk; }
    }

    // Wire -> state-array bit position (fixed permutation; non-local wires high;
    // bit position 0 is never a gap -> float4 global access stays contiguous).
    static const int wireToPos[16] = {4,3,2,9,8,7,1,0,12,11,10,6,5,15,14,13};
    int posToWire[16];
    for (int w = 0; w < 16; ++w) posToWire[wireToPos[w]] = w;
    static const int WIN[4][3] = {{13,14,15},{8,9,10},{3,4,5},{11,12,13}};

    // Schedule: only same-layer reordering (same-layer gates always commute).
    int pendLayer[4] = {0, 0, 0, 0};
    int totalPend = 0;
    for (int i = 0; i < ng; ++i)
        if (!gl[i].pruned) { pendLayer[gl[i].layer]++; totalPend++; }

    PassMeta pms[12];
    int np = 0;
    while ((totalPend > 0 || np < 2) && np < 12) {
        PassMeta& M = pms[np];
        memset(&M, 0, sizeof(M));
        const int* W = WIN[np % 4];
        int gp[3], gw[3];
        for (int k = 0; k < 3; ++k) { gp[k] = wireToPos[W[k]]; gw[k] = W[k]; }
        for (int a = 0; a < 3; ++a)
            for (int b = a + 1; b < 3; ++b)
                if (gp[b] < gp[a]) {
                    int t = gp[a]; gp[a] = gp[b]; gp[b] = t;
                    t = gw[a]; gw[a] = gw[b]; gw[b] = t;
                }
        uint16_t Smask = 0xFFFF;
        for (int k = 0; k < 3; ++k) {
            Smask &= (uint16_t)~(1u << gw[k]);
            M.gap[k] = (uint8_t)gp[k];
            M.nlw[k] = (uint8_t)gw[k];
        }
        int packedOfWire[16];
        for (int w = 0; w < 16; ++w) packedOfWire[w] = -1;
        int t = 0;
        for (int pos = 0; pos < 16; ++pos) {
            if (pos == gp[0] || pos == gp[1] || pos == gp[2]) continue;
            int w = posToWire[pos];
            M.wire_of_bit[t] = (uint8_t)w;
            packedOfWire[w] = t;
            ++t;
        }
        // Select gates for this pass (cross-layer order preserved).
        int sel[24]; int nsel = 0;
        for (int i = 0; i < ng && nsel < 24; ++i) {
            if (gl[i].pruned || gl[i].sched) continue;
            bool lowerDone = true;
            for (int m2 = 1; m2 < gl[i].layer; ++m2)
                if (pendLayer[m2] > 0) { lowerDone = false; break; }
            if (!lowerDone) continue;
            if (gl[i].D & ~Smask) continue;
            gl[i].sched = true;
            pendLayer[gl[i].layer]--; totalPend--;
            sel[nsel++] = i;
        }
        // Map a gate's (D,R) to packed-local (mask,row,nl-chunk-parity-mask).
        auto tolocal = [&](const G& g, uint16_t& m, uint16_t& r, uint8_t& nl) {
            m = 0; r = 0; nl = 0;
            for (int w = 0; w < 16; ++w) {
                if ((g.D >> w) & 1) m |= (uint16_t)(1u << packedOfWire[w]);
                if (((g.R >> w) & 1) && packedOfWire[w] >= 0)
                    r |= (uint16_t)(1u << packedOfWire[w]);
            }
            for (int k = 0; k < 3; ++k)
                if ((g.R >> gw[k]) & 1) nl |= (uint8_t)(1u << k);
        };
        // Cluster consecutive gate pairs into dim-2 cosets.
        M.nclusters = 0;
        for (int s = 0; s < nsel; s += 2) {
            int ci = M.nclusters++;
            uint16_t mA, rA; uint8_t nlA;
            tolocal(gl[sel[s]], mA, rA, nlA);
            bool hasB = (s + 1) < nsel;
            uint16_t mB = 0, rB = 0; uint8_t nlB = 0;
            if (hasB) tolocal(gl[sel[s + 1]], mB, rB, nlB);
            uint16_t xm = mA, ym; int pat;
            if (!hasB || mB == mA) {
                ym = (xm == 1u) ? 2u : 1u;   // any bit linearly indep of xm
                pat = 0;
            } else {
                ym = mB;
                int px0 = 31 - __builtin_clz((unsigned)xm);
                if ((ym >> px0) & 1) { ym ^= xm; pat = 2; } else pat = 1;
            }
            int px = 31 - __builtin_clz((unsigned)xm);
            int py = 31 - __builtin_clz((unsigned)ym);
            int qa = px < py ? px : py, qb = px < py ? py : px;
            M.cx[ci] = xm; M.cy[ci] = ym;
            M.cq0[ci] = (uint8_t)qa; M.cq1[ci] = (uint8_t)qb;
            M.gA[ci] = (uint8_t)gl[sel[s]].gidx;
            M.gB[ci] = hasB ? (uint8_t)gl[sel[s + 1]].gidx : (uint8_t)0xFF;
            M.rowA[ci] = rA; M.nlA[ci] = nlA;
            M.rowB[ci] = hasB ? rB : (uint16_t)0;
            M.nlB[ci]  = hasB ? nlB : (uint8_t)0;
            M.pyA[ci]  = (uint8_t)__builtin_parity((unsigned)(ym & rA));
            M.patB[ci] = (uint8_t)pat;
            M.poffB[ci] = hasB
                ? (uint8_t)__builtin_parity((unsigned)(((pat == 0) ? ym : xm) & rB))
                : (uint8_t)0;
        }
        {   // measurement masks (used only if this pass ends up last)
            uint16_t r = 0; uint8_t nl = 0;
            for (int w = 0; w < 16; ++w)
                if (((Rmeas >> w) & 1) && packedOfWire[w] >= 0)
                    r |= (uint16_t)(1u << packedOfWire[w]);
            for (int k = 0; k < 3; ++k)
                if ((Rmeas >> gw[k]) & 1) nl |= (uint8_t)(1u << k);
            M.meas_row_local = r; M.meas_nl = nl;
        }
        ++np;
    }

    precompute_kernel<<<dim3(64), dim3(512), 0, stream>>>(X, Wt, Bs, Ug, out);
    for (int g = 0; g < ngroups; ++g) {
        const float2* ug = Ug + (size_t)g * group * 256;
        float* og = out + (size_t)g * group;
        dim3 grid(group * 8);
        for (int p = 0; p < np; ++p) {
            if (p == 0)
                pass_kernel<0><<<grid, dim3(512), 0, stream>>>(ug, state, og, pms[p]);
            else if (p == np - 1)
                pass_kernel<2><<<grid, dim3(512), 0, stream>>>(ug, state, og, pms[p]);
            else
                pass_kernel<1><<<grid, dim3(512), 0, stream>>>(ug, state, og, pms[p]);
        }
    }

    (void)in_sizes; (void)n_in; (void)out_size; (void)ws_size;
}